// Round 1
// baseline (358.837 us; speedup 1.0000x reference)
//
#include <hip/hip_runtime.h>
#include <math.h>

// InteractionGate: N=500000 agents, H=64, D=32.
// Reduction: d1 == 0 always; d2[i] = ||goal[i]-position[i]||;
// new_h[i][j] = sigmoid(C[j] + d2[i]*Wd[j] + dot(h[i], W2[j][:])), W2[j][k]=W_fc[j][64+k].
// h_out[idx] = h[idx]. goal_out (64) computed once.
//
// R5: occupancy lever. R4 post-mortem: all utilization counters low
// (VALUBusy 11%, Occupancy 37%, HBM 29%) -> latency-bound equilibrium at
// ~3.2 TB/s combined, 55% of the copy ceiling. Per-wave in-flight is only
// ~10 VMEM ops; 16 waves/CU under-subscribe the memory system. VGPR=60 and
// LDS=8.7KB both fit 8 blocks/CU (512/64=8 waves/SIMD, 8*8.7=70KB<160KB),
// so double resident waves: __launch_bounds__(256,8), grid 2048.
// Everything else identical to R4 (single-lever change).

#define AH 64
#define AD 32

typedef __attribute__((ext_vector_type(8))) short bf16x8;
typedef __attribute__((ext_vector_type(4))) float f32x4;
typedef __attribute__((ext_vector_type(2))) float f32x2;

__device__ __forceinline__ float sigmoid_fast(float x) {
    return __builtin_amdgcn_rcpf(1.0f + __expf(-x));
}

__device__ __forceinline__ short f2bf(float f) {
    union { float f; unsigned u; } v; v.f = f;
    unsigned r = v.u + 0x7fffu + ((v.u >> 16) & 1u);
    return (short)(r >> 16);
}

// ws layout (floats): [0:64) C, [64:128) Wd, [128:128+2048) = bf16x8 wfrag[8][64].
__global__ void ig_precompute(
    const float* __restrict__ h,      // N x 64
    const float* __restrict__ ghs,    // 64
    const float* __restrict__ goal,   // N x 2
    const float* __restrict__ pos,    // N x 2
    const float* __restrict__ W_emb,  // 32 x 2
    const float* __restrict__ b_emb,  // 32
    const float* __restrict__ W_fc,   // 64 x 192
    const float* __restrict__ b_fc,   // 64
    const int*   __restrict__ idx_p,
    float* __restrict__ out_goal,     // 64
    float* __restrict__ ws)
{
    const int l = threadIdx.x;        // 0..63
    if (l >= 64) return;
    const int idx = idx_p[0];
    const int m15 = l & 15, q = l >> 4;

    // --- C[l], Wd[l], goal_out[l] ---
    const float* wrow = W_fc + l * 192;
    const f32x4* w4  = (const f32x4*)wrow;
    const f32x4* wg4 = (const f32x4*)(wrow + AH);
    const f32x4* h4  = (const f32x4*)(h + (size_t)idx * AH);
    const f32x4* g4  = (const f32x4*)ghs;
    float c = b_fc[l], g = b_fc[l];
    #pragma unroll
    for (int m = 0; m < 16; ++m) {
        const f32x4 hv = h4[m], wv = w4[m];
        const float d = hv[0]*wv[0] + hv[1]*wv[1] + hv[2]*wv[2] + hv[3]*wv[3];
        c += d; g += d;
        const f32x4 gv = g4[m], wv2 = wg4[m];
        g += gv[0]*wv2[0] + gv[1]*wv2[1] + gv[2]*wv2[2] + gv[3]*wv2[3];
    }
    const float px = pos[(size_t)idx*2+0], py = pos[(size_t)idx*2+1];
    const float gx = goal[(size_t)idx*2+0], gy = goal[(size_t)idx*2+1];
    const float dgx = px - gx, dgy = py - gy;
    const float dg = sqrtf(dgx*dgx + dgy*dgy);
    const float* wd1 = wrow + 128;
    const float* wd2 = wrow + 160;
    float wd = 0.f;
    #pragma unroll
    for (int k = 0; k < AD; ++k) {
        const float wsum = W_emb[2*k] + W_emb[2*k+1];
        const float be   = b_emb[k];
        const float w12  = wd1[k] + wd2[k];
        c  += be * w12;
        wd += wsum * wd2[k];
        g  += (dg * wsum + be) * w12;
    }
    ws[l]      = c;
    ws[64 + l] = wd;
    out_goal[l] = sigmoid_fast(g);

    // --- weight A-frags: wfrag[f=mg*2+cc][lane] = W2[mg*16+m15][cc*32+q*8 .. +7] ---
    bf16x8* wf = (bf16x8*)(ws + 128);
    #pragma unroll
    for (int f = 0; f < 8; ++f) {
        const int mg = f >> 1, cc = f & 1;
        const float* src = W_fc + (size_t)(mg*16 + m15) * 192 + AH + cc*32 + q*8;
        const f32x4 s0 = *(const f32x4*)(src);
        const f32x4 s1 = *(const f32x4*)(src + 4);
        bf16x8 b;
        #pragma unroll
        for (int j = 0; j < 4; ++j) { b[j] = f2bf(s0[j]); b[4+j] = f2bf(s1[j]); }
        wf[f * 64 + l] = b;
    }
}

__global__ __launch_bounds__(256, 8) void ig_main(
    const float* __restrict__ h,      // N x 64
    const float* __restrict__ goal,   // N x 2
    const float* __restrict__ pos,    // N x 2
    const float* __restrict__ ws,     // C, Wd, wfrag
    const int*   __restrict__ idx_p,
    float* __restrict__ out,          // N x 64
    int n_tiles, int total_waves)
{
    __shared__ bf16x8 wlds[8][64];              // 8 KB
    __shared__ __align__(16) float cw[128];     // C, Wd

    const int tid  = threadIdx.x;
    const int w    = tid >> 6;
    const int lane = tid & 63;
    const int m15  = lane & 15;
    const int q    = lane >> 4;
    const int idx  = idx_p[0];

    // Stage ws -> LDS: 128 floats + 512 x 16B chunks.
    if (tid < 128) cw[tid] = ws[tid];
    {
        const f32x4* src = (const f32x4*)(ws + 128);
        f32x4* dst = (f32x4*)wlds;
        dst[tid]       = src[tid];
        dst[tid + 256] = src[tid + 256];
    }
    __syncthreads();

    const int wid = blockIdx.x * 4 + w;
    int t = wid;
    f32x4 b0 = {}, b1 = {}, b2 = {}, b3 = {};
    f32x2 gv = {}, pv = {};
    if (t < n_tiles) {
        const int n0 = t * 16 + m15;
        const float* hr = h + (size_t)n0 * AH;
        b0 = *(const f32x4*)(hr + q*8);
        b1 = *(const f32x4*)(hr + q*8 + 4);
        b2 = *(const f32x4*)(hr + 32 + q*8);
        b3 = *(const f32x4*)(hr + 32 + q*8 + 4);
        gv = *(const f32x2*)(goal + 2*(size_t)n0);
        pv = *(const f32x2*)(pos  + 2*(size_t)n0);
    }

    while (t < n_tiles) {
        const int tn = t + total_waves;
        const int tload = (tn < n_tiles) ? tn : t;
        const int nl = tload * 16 + m15;
        const float* hrn = h + (size_t)nl * AH;
        // Prefetch loads issue BEFORE this iteration's stores -> waiting for
        // them next iteration does not drain the stores (in-order vmcnt).
        const f32x4 nb0 = *(const f32x4*)(hrn + q*8);
        const f32x4 nb1 = *(const f32x4*)(hrn + q*8 + 4);
        const f32x4 nb2 = *(const f32x4*)(hrn + 32 + q*8);
        const f32x4 nb3 = *(const f32x4*)(hrn + 32 + q*8 + 4);
        const f32x2 ngv = *(const f32x2*)(goal + 2*(size_t)nl);
        const f32x2 npv = *(const f32x2*)(pos  + 2*(size_t)nl);

        const int agent = t * 16 + m15;
        const float dx = gv[0] - pv[0], dy = gv[1] - pv[1];
        const float d2v = sqrtf(dx*dx + dy*dy);

        bf16x8 bf0, bf1;
        #pragma unroll
        for (int j = 0; j < 4; ++j) {
            bf0[j] = f2bf(b0[j]); bf0[4+j] = f2bf(b1[j]);
            bf1[j] = f2bf(b2[j]); bf1[4+j] = f2bf(b3[j]);
        }

        const size_t rb = (size_t)agent * AH;
        #pragma unroll
        for (int mg = 0; mg < 4; ++mg) {
            const f32x4 c4 = *(const f32x4*)&cw[mg*16 + q*4];
            const f32x4 d4 = *(const f32x4*)&cw[64 + mg*16 + q*4];
            f32x4 acc;
            #pragma unroll
            for (int r = 0; r < 4; ++r) acc[r] = c4[r] + d2v * d4[r];
            acc = __builtin_amdgcn_mfma_f32_16x16x32_bf16(wlds[mg*2+0][lane], bf0, acc, 0, 0, 0);
            acc = __builtin_amdgcn_mfma_f32_16x16x32_bf16(wlds[mg*2+1][lane], bf1, acc, 0, 0, 0);

            f32x4 vv;
            #pragma unroll
            for (int r = 0; r < 4; ++r) vv[r] = sigmoid_fast(acc[r]);
            if (agent == idx) vv = *(const f32x4*)(h + rb + mg*16 + q*4);
            *(f32x4*)(out + rb + mg*16 + q*4) = vv;   // plain cached store
        }

        t = tn;
        b0 = nb0; b1 = nb1; b2 = nb2; b3 = nb3;
        gv = ngv; pv = npv;
    }
}

extern "C" void kernel_launch(void* const* d_in, const int* in_sizes, int n_in,
                              void* d_out, int out_size, void* d_ws, size_t ws_size,
                              hipStream_t stream) {
    const float* h     = (const float*)d_in[0];
    const float* ghs   = (const float*)d_in[1];
    const float* goal  = (const float*)d_in[2];
    const float* pos   = (const float*)d_in[3];
    const float* W_emb = (const float*)d_in[4];
    const float* b_emb = (const float*)d_in[5];
    const float* W_fc  = (const float*)d_in[6];
    const float* b_fc  = (const float*)d_in[7];
    const int*   idx_p = (const int*)d_in[8];

    const int N = in_sizes[0] / AH;          // 500000
    float* out      = (float*)d_out;
    float* out_goal = out + (size_t)N * AH;
    float* ws       = (float*)d_ws;          // 128 + 512*4 floats = 8.5 KB

    ig_precompute<<<1, 64, 0, stream>>>(h, ghs, goal, pos, W_emb, b_emb, W_fc, b_fc,
                                        idx_p, out_goal, ws);

    const int n_tiles = N / 16;              // 31250
    const int blocks = 2048;                 // 8 blocks/CU (VGPR<=64, LDS 70KB/CU)
    const int total_waves = blocks * 4;
    ig_main<<<blocks, 256, 0, stream>>>(h, goal, pos, ws, idx_p, out,
                                        n_tiles, total_waves);
}

// Round 2
// 266.214 us; speedup vs baseline: 1.3479x; 1.3479x over previous
//
#include <hip/hip_runtime.h>
#include <math.h>

// InteractionGate: N=500000 agents, H=64, D=32.
// Reduction: d1 == 0 always; d2[i] = ||goal[i]-position[i]||;
// new_h[i][j] = sigmoid(C[j] + d2[i]*Wd[j] + dot(h[i], W2[j][:])), W2[j][k]=W_fc[j][64+k].
// h_out[idx] = h[idx]. goal_out (64) computed once.
//
// R6: revert R5's occupancy change (it destroyed both codegen and L3
// locality: VGPR 60->32 sank the prefetch, FETCH 71->293MB from the
// 264MB-vs-256MB-L3 cyclic-LRU cliff). Back to grid 1024 + bounds(256,4),
// and instead raise PER-WAVE memory-level parallelism: depth-2 prefetch
// (3 rotating register sets, loads issued 2 iterations ahead). Wave count
// and sweep frontier unchanged -> traffic must stay ~71MB fetch / 128MB
// write; only the latency equilibrium moves.

#define AH 64
#define AD 32

typedef __attribute__((ext_vector_type(8))) short bf16x8;
typedef __attribute__((ext_vector_type(4))) float f32x4;
typedef __attribute__((ext_vector_type(2))) float f32x2;

__device__ __forceinline__ float sigmoid_fast(float x) {
    return __builtin_amdgcn_rcpf(1.0f + __expf(-x));
}

__device__ __forceinline__ short f2bf(float f) {
    union { float f; unsigned u; } v; v.f = f;
    unsigned r = v.u + 0x7fffu + ((v.u >> 16) & 1u);
    return (short)(r >> 16);
}

// ws layout (floats): [0:64) C, [64:128) Wd, [128:128+2048) = bf16x8 wfrag[8][64].
__global__ void ig_precompute(
    const float* __restrict__ h,      // N x 64
    const float* __restrict__ ghs,    // 64
    const float* __restrict__ goal,   // N x 2
    const float* __restrict__ pos,    // N x 2
    const float* __restrict__ W_emb,  // 32 x 2
    const float* __restrict__ b_emb,  // 32
    const float* __restrict__ W_fc,   // 64 x 192
    const float* __restrict__ b_fc,   // 64
    const int*   __restrict__ idx_p,
    float* __restrict__ out_goal,     // 64
    float* __restrict__ ws)
{
    const int l = threadIdx.x;        // 0..63
    if (l >= 64) return;
    const int idx = idx_p[0];
    const int m15 = l & 15, q = l >> 4;

    // --- C[l], Wd[l], goal_out[l] ---
    const float* wrow = W_fc + l * 192;
    const f32x4* w4  = (const f32x4*)wrow;
    const f32x4* wg4 = (const f32x4*)(wrow + AH);
    const f32x4* h4  = (const f32x4*)(h + (size_t)idx * AH);
    const f32x4* g4  = (const f32x4*)ghs;
    float c = b_fc[l], g = b_fc[l];
    #pragma unroll
    for (int m = 0; m < 16; ++m) {
        const f32x4 hv = h4[m], wv = w4[m];
        const float d = hv[0]*wv[0] + hv[1]*wv[1] + hv[2]*wv[2] + hv[3]*wv[3];
        c += d; g += d;
        const f32x4 gv = g4[m], wv2 = wg4[m];
        g += gv[0]*wv2[0] + gv[1]*wv2[1] + gv[2]*wv2[2] + gv[3]*wv2[3];
    }
    const float px = pos[(size_t)idx*2+0], py = pos[(size_t)idx*2+1];
    const float gx = goal[(size_t)idx*2+0], gy = goal[(size_t)idx*2+1];
    const float dgx = px - gx, dgy = py - gy;
    const float dg = sqrtf(dgx*dgx + dgy*dgy);
    const float* wd1 = wrow + 128;
    const float* wd2 = wrow + 160;
    float wd = 0.f;
    #pragma unroll
    for (int k = 0; k < AD; ++k) {
        const float wsum = W_emb[2*k] + W_emb[2*k+1];
        const float be   = b_emb[k];
        const float w12  = wd1[k] + wd2[k];
        c  += be * w12;
        wd += wsum * wd2[k];
        g  += (dg * wsum + be) * w12;
    }
    ws[l]      = c;
    ws[64 + l] = wd;
    out_goal[l] = sigmoid_fast(g);

    // --- weight A-frags: wfrag[f=mg*2+cc][lane] = W2[mg*16+m15][cc*32+q*8 .. +7] ---
    bf16x8* wf = (bf16x8*)(ws + 128);
    #pragma unroll
    for (int f = 0; f < 8; ++f) {
        const int mg = f >> 1, cc = f & 1;
        const float* src = W_fc + (size_t)(mg*16 + m15) * 192 + AH + cc*32 + q*8;
        const f32x4 s0 = *(const f32x4*)(src);
        const f32x4 s1 = *(const f32x4*)(src + 4);
        bf16x8 b;
        #pragma unroll
        for (int j = 0; j < 4; ++j) { b[j] = f2bf(s0[j]); b[4+j] = f2bf(s1[j]); }
        wf[f * 64 + l] = b;
    }
}

// Load one 16-agent tile's h rows + goal/pos into a register set.
#define LOAD_TILE(T, v0, v1, v2, v3, vg, vp) do {                         \
    const int nn_ = (T) * 16 + m15;                                       \
    const float* hp_ = h + (size_t)nn_ * AH;                              \
    v0 = *(const f32x4*)(hp_ + q*8);                                      \
    v1 = *(const f32x4*)(hp_ + q*8 + 4);                                  \
    v2 = *(const f32x4*)(hp_ + 32 + q*8);                                 \
    v3 = *(const f32x4*)(hp_ + 32 + q*8 + 4);                             \
    vg = *(const f32x2*)(goal + 2*(size_t)nn_);                           \
    vp = *(const f32x2*)(pos  + 2*(size_t)nn_);                           \
} while (0)

__global__ __launch_bounds__(256, 4) void ig_main(
    const float* __restrict__ h,      // N x 64
    const float* __restrict__ goal,   // N x 2
    const float* __restrict__ pos,    // N x 2
    const float* __restrict__ ws,     // C, Wd, wfrag
    const int*   __restrict__ idx_p,
    float* __restrict__ out,          // N x 64
    int n_tiles, int total_waves)
{
    __shared__ bf16x8 wlds[8][64];              // 8 KB
    __shared__ __align__(16) float cw[128];     // C, Wd

    const int tid  = threadIdx.x;
    const int w    = tid >> 6;
    const int lane = tid & 63;
    const int m15  = lane & 15;
    const int q    = lane >> 4;
    const int idx  = idx_p[0];

    // Stage ws -> LDS: 128 floats + 512 x 16B chunks.
    if (tid < 128) cw[tid] = ws[tid];
    {
        const f32x4* src = (const f32x4*)(ws + 128);
        f32x4* dst = (f32x4*)wlds;
        dst[tid]       = src[tid];
        dst[tid + 256] = src[tid + 256];
    }
    __syncthreads();

    const int wid = blockIdx.x * 4 + w;
    const int TW  = total_waves;

    // Depth-2 software pipeline: A = tile t (consumed now),
    // B = tile t+TW, C = tile t+2TW (issued this iteration).
    int t = wid;                                 // wid < 4096 <= n_tiles always
    f32x4 A0, A1, A2, A3; f32x2 Ag, Ap;
    f32x4 B0, B1, B2, B3; f32x2 Bg, Bp;
    LOAD_TILE(t, A0, A1, A2, A3, Ag, Ap);
    LOAD_TILE(t + TW < n_tiles ? t + TW : t, B0, B1, B2, B3, Bg, Bp);

    while (t < n_tiles) {
        // Issue far prefetch (2 iterations ahead) BEFORE this iteration's
        // stores -> waiting on it later never drains the stores.
        const int tf = t + 2 * TW;
        const int tl = (tf < n_tiles) ? tf : t;  // clamp: harmless reload
        f32x4 C0, C1, C2, C3; f32x2 Cg, Cp;
        LOAD_TILE(tl, C0, C1, C2, C3, Cg, Cp);

        const int agent = t * 16 + m15;
        const float dx = Ag[0] - Ap[0], dy = Ag[1] - Ap[1];
        const float d2v = sqrtf(dx*dx + dy*dy);

        bf16x8 bf0, bf1;
        #pragma unroll
        for (int j = 0; j < 4; ++j) {
            bf0[j] = f2bf(A0[j]); bf0[4+j] = f2bf(A1[j]);
            bf1[j] = f2bf(A2[j]); bf1[4+j] = f2bf(A3[j]);
        }

        const size_t rb = (size_t)agent * AH;
        #pragma unroll
        for (int mg = 0; mg < 4; ++mg) {
            const f32x4 c4 = *(const f32x4*)&cw[mg*16 + q*4];
            const f32x4 d4 = *(const f32x4*)&cw[64 + mg*16 + q*4];
            f32x4 acc;
            #pragma unroll
            for (int r = 0; r < 4; ++r) acc[r] = c4[r] + d2v * d4[r];
            acc = __builtin_amdgcn_mfma_f32_16x16x32_bf16(wlds[mg*2+0][lane], bf0, acc, 0, 0, 0);
            acc = __builtin_amdgcn_mfma_f32_16x16x32_bf16(wlds[mg*2+1][lane], bf1, acc, 0, 0, 0);

            f32x4 vv;
            #pragma unroll
            for (int r = 0; r < 4; ++r) vv[r] = sigmoid_fast(acc[r]);
            if (agent == idx) vv = *(const f32x4*)(h + rb + mg*16 + q*4);
            *(f32x4*)(out + rb + mg*16 + q*4) = vv;   // plain cached store
        }

        t += TW;
        A0 = B0; A1 = B1; A2 = B2; A3 = B3; Ag = Bg; Ap = Bp;
        B0 = C0; B1 = C1; B2 = C2; B3 = C3; Bg = Cg; Bp = Cp;
    }
}

extern "C" void kernel_launch(void* const* d_in, const int* in_sizes, int n_in,
                              void* d_out, int out_size, void* d_ws, size_t ws_size,
                              hipStream_t stream) {
    const float* h     = (const float*)d_in[0];
    const float* ghs   = (const float*)d_in[1];
    const float* goal  = (const float*)d_in[2];
    const float* pos   = (const float*)d_in[3];
    const float* W_emb = (const float*)d_in[4];
    const float* b_emb = (const float*)d_in[5];
    const float* W_fc  = (const float*)d_in[6];
    const float* b_fc  = (const float*)d_in[7];
    const int*   idx_p = (const int*)d_in[8];

    const int N = in_sizes[0] / AH;          // 500000
    float* out      = (float*)d_out;
    float* out_goal = out + (size_t)N * AH;
    float* ws       = (float*)d_ws;          // 128 + 512*4 floats = 8.5 KB

    ig_precompute<<<1, 64, 0, stream>>>(h, ghs, goal, pos, W_emb, b_emb, W_fc, b_fc,
                                        idx_p, out_goal, ws);

    const int n_tiles = N / 16;              // 31250
    const int blocks = 1024;                 // exact 4 blocks/CU fit
    const int total_waves = blocks * 4;
    ig_main<<<blocks, 256, 0, stream>>>(h, goal, pos, ws, idx_p, out,
                                        n_tiles, total_waves);
}

// Round 3
// 262.956 us; speedup vs baseline: 1.3646x; 1.0124x over previous
//
#include <hip/hip_runtime.h>
#include <math.h>

// InteractionGate: N=500000 agents, H=64, D=32.
// Reduction: d1 == 0 always; d2[i] = ||goal[i]-position[i]||;
// new_h[i][j] = sigmoid(C[j] + d2[i]*Wd[j] + dot(h[i], W2[j][:])), W2[j][k]=W_fc[j][64+k].
// h_out[idx] = h[idx]. goal_out (64) computed once.
//
// R7: R6 post-mortem showed depth-2 prefetch DID raise memory throughput
// (2.39 -> 2.85 TB/s) but the tail clamp `tl = tf<n ? tf : t` made every
// wave's last ~2 iterations re-load its own 4KB tile from HBM: 4096 waves
// x ~2 x 4KB ~= 33MB of scattered redundant FETCH (71->119MB), eating the
// gain. Fix: clamp the far prefetch to h rows 0..15 -- the SAME 4KB region
// for all waves, so it stays L2-hot and costs ~nothing. Everything else
// identical to R6.

#define AH 64
#define AD 32

typedef __attribute__((ext_vector_type(8))) short bf16x8;
typedef __attribute__((ext_vector_type(4))) float f32x4;
typedef __attribute__((ext_vector_type(2))) float f32x2;

__device__ __forceinline__ float sigmoid_fast(float x) {
    return __builtin_amdgcn_rcpf(1.0f + __expf(-x));
}

__device__ __forceinline__ short f2bf(float f) {
    union { float f; unsigned u; } v; v.f = f;
    unsigned r = v.u + 0x7fffu + ((v.u >> 16) & 1u);
    return (short)(r >> 16);
}

// ws layout (floats): [0:64) C, [64:128) Wd, [128:128+2048) = bf16x8 wfrag[8][64].
__global__ void ig_precompute(
    const float* __restrict__ h,      // N x 64
    const float* __restrict__ ghs,    // 64
    const float* __restrict__ goal,   // N x 2
    const float* __restrict__ pos,    // N x 2
    const float* __restrict__ W_emb,  // 32 x 2
    const float* __restrict__ b_emb,  // 32
    const float* __restrict__ W_fc,   // 64 x 192
    const float* __restrict__ b_fc,   // 64
    const int*   __restrict__ idx_p,
    float* __restrict__ out_goal,     // 64
    float* __restrict__ ws)
{
    const int l = threadIdx.x;        // 0..63
    if (l >= 64) return;
    const int idx = idx_p[0];
    const int m15 = l & 15, q = l >> 4;

    // --- C[l], Wd[l], goal_out[l] ---
    const float* wrow = W_fc + l * 192;
    const f32x4* w4  = (const f32x4*)wrow;
    const f32x4* wg4 = (const f32x4*)(wrow + AH);
    const f32x4* h4  = (const f32x4*)(h + (size_t)idx * AH);
    const f32x4* g4  = (const f32x4*)ghs;
    float c = b_fc[l], g = b_fc[l];
    #pragma unroll
    for (int m = 0; m < 16; ++m) {
        const f32x4 hv = h4[m], wv = w4[m];
        const float d = hv[0]*wv[0] + hv[1]*wv[1] + hv[2]*wv[2] + hv[3]*wv[3];
        c += d; g += d;
        const f32x4 gv = g4[m], wv2 = wg4[m];
        g += gv[0]*wv2[0] + gv[1]*wv2[1] + gv[2]*wv2[2] + gv[3]*wv2[3];
    }
    const float px = pos[(size_t)idx*2+0], py = pos[(size_t)idx*2+1];
    const float gx = goal[(size_t)idx*2+0], gy = goal[(size_t)idx*2+1];
    const float dgx = px - gx, dgy = py - gy;
    const float dg = sqrtf(dgx*dgx + dgy*dgy);
    const float* wd1 = wrow + 128;
    const float* wd2 = wrow + 160;
    float wd = 0.f;
    #pragma unroll
    for (int k = 0; k < AD; ++k) {
        const float wsum = W_emb[2*k] + W_emb[2*k+1];
        const float be   = b_emb[k];
        const float w12  = wd1[k] + wd2[k];
        c  += be * w12;
        wd += wsum * wd2[k];
        g  += (dg * wsum + be) * w12;
    }
    ws[l]      = c;
    ws[64 + l] = wd;
    out_goal[l] = sigmoid_fast(g);

    // --- weight A-frags: wfrag[f=mg*2+cc][lane] = W2[mg*16+m15][cc*32+q*8 .. +7] ---
    bf16x8* wf = (bf16x8*)(ws + 128);
    #pragma unroll
    for (int f = 0; f < 8; ++f) {
        const int mg = f >> 1, cc = f & 1;
        const float* src = W_fc + (size_t)(mg*16 + m15) * 192 + AH + cc*32 + q*8;
        const f32x4 s0 = *(const f32x4*)(src);
        const f32x4 s1 = *(const f32x4*)(src + 4);
        bf16x8 b;
        #pragma unroll
        for (int j = 0; j < 4; ++j) { b[j] = f2bf(s0[j]); b[4+j] = f2bf(s1[j]); }
        wf[f * 64 + l] = b;
    }
}

// Load one 16-agent tile's h rows + goal/pos into a register set.
// T is a ROW-BASE (tile*16), pre-clamped by the caller.
#define LOAD_TILE(T, v0, v1, v2, v3, vg, vp) do {                         \
    const int nn_ = (T) + m15;                                            \
    const float* hp_ = h + (size_t)nn_ * AH;                              \
    v0 = *(const f32x4*)(hp_ + q*8);                                      \
    v1 = *(const f32x4*)(hp_ + q*8 + 4);                                  \
    v2 = *(const f32x4*)(hp_ + 32 + q*8);                                 \
    v3 = *(const f32x4*)(hp_ + 32 + q*8 + 4);                             \
    vg = *(const f32x2*)(goal + 2*(size_t)nn_);                           \
    vp = *(const f32x2*)(pos  + 2*(size_t)nn_);                           \
} while (0)

__global__ __launch_bounds__(256, 4) void ig_main(
    const float* __restrict__ h,      // N x 64
    const float* __restrict__ goal,   // N x 2
    const float* __restrict__ pos,    // N x 2
    const float* __restrict__ ws,     // C, Wd, wfrag
    const int*   __restrict__ idx_p,
    float* __restrict__ out,          // N x 64
    int n_tiles, int total_waves)
{
    __shared__ bf16x8 wlds[8][64];              // 8 KB
    __shared__ __align__(16) float cw[128];     // C, Wd

    const int tid  = threadIdx.x;
    const int w    = tid >> 6;
    const int lane = tid & 63;
    const int m15  = lane & 15;
    const int q    = lane >> 4;
    const int idx  = idx_p[0];

    // Stage ws -> LDS: 128 floats + 512 x 16B chunks.
    if (tid < 128) cw[tid] = ws[tid];
    {
        const f32x4* src = (const f32x4*)(ws + 128);
        f32x4* dst = (f32x4*)wlds;
        dst[tid]       = src[tid];
        dst[tid + 256] = src[tid + 256];
    }
    __syncthreads();

    const int wid = blockIdx.x * 4 + w;
    const int TW  = total_waves;

    // Depth-2 software pipeline: A = tile t (consumed now),
    // B = tile t+TW, C = tile t+2TW (issued this iteration).
    // Out-of-range prefetches clamp to rows 0..15 -- a single 4KB region
    // shared by ALL waves, so it stays L2-hot (R6's per-wave clamp was
    // 33MB of scattered redundant HBM fetch).
    int t = wid;                                 // wid < 4096 <= n_tiles always
    f32x4 A0, A1, A2, A3; f32x2 Ag, Ap;
    f32x4 B0, B1, B2, B3; f32x2 Bg, Bp;
    LOAD_TILE(t * 16, A0, A1, A2, A3, Ag, Ap);
    LOAD_TILE(t + TW < n_tiles ? (t + TW) * 16 : 0, B0, B1, B2, B3, Bg, Bp);

    while (t < n_tiles) {
        // Issue far prefetch (2 iterations ahead) BEFORE this iteration's
        // stores -> waiting on it later never drains the stores.
        const int tf = t + 2 * TW;
        const int rowbase = (tf < n_tiles) ? tf * 16 : 0;  // shared hot clamp
        f32x4 C0, C1, C2, C3; f32x2 Cg, Cp;
        LOAD_TILE(rowbase, C0, C1, C2, C3, Cg, Cp);

        const int agent = t * 16 + m15;
        const float dx = Ag[0] - Ap[0], dy = Ag[1] - Ap[1];
        const float d2v = sqrtf(dx*dx + dy*dy);

        bf16x8 bf0, bf1;
        #pragma unroll
        for (int j = 0; j < 4; ++j) {
            bf0[j] = f2bf(A0[j]); bf0[4+j] = f2bf(A1[j]);
            bf1[j] = f2bf(A2[j]); bf1[4+j] = f2bf(A3[j]);
        }

        const size_t rb = (size_t)agent * AH;
        #pragma unroll
        for (int mg = 0; mg < 4; ++mg) {
            const f32x4 c4 = *(const f32x4*)&cw[mg*16 + q*4];
            const f32x4 d4 = *(const f32x4*)&cw[64 + mg*16 + q*4];
            f32x4 acc;
            #pragma unroll
            for (int r = 0; r < 4; ++r) acc[r] = c4[r] + d2v * d4[r];
            acc = __builtin_amdgcn_mfma_f32_16x16x32_bf16(wlds[mg*2+0][lane], bf0, acc, 0, 0, 0);
            acc = __builtin_amdgcn_mfma_f32_16x16x32_bf16(wlds[mg*2+1][lane], bf1, acc, 0, 0, 0);

            f32x4 vv;
            #pragma unroll
            for (int r = 0; r < 4; ++r) vv[r] = sigmoid_fast(acc[r]);
            if (agent == idx) vv = *(const f32x4*)(h + rb + mg*16 + q*4);
            *(f32x4*)(out + rb + mg*16 + q*4) = vv;   // plain cached store
        }

        t += TW;
        A0 = B0; A1 = B1; A2 = B2; A3 = B3; Ag = Bg; Ap = Bp;
        B0 = C0; B1 = C1; B2 = C2; B3 = C3; Bg = Cg; Bp = Cp;
    }
}

extern "C" void kernel_launch(void* const* d_in, const int* in_sizes, int n_in,
                              void* d_out, int out_size, void* d_ws, size_t ws_size,
                              hipStream_t stream) {
    const float* h     = (const float*)d_in[0];
    const float* ghs   = (const float*)d_in[1];
    const float* goal  = (const float*)d_in[2];
    const float* pos   = (const float*)d_in[3];
    const float* W_emb = (const float*)d_in[4];
    const float* b_emb = (const float*)d_in[5];
    const float* W_fc  = (const float*)d_in[6];
    const float* b_fc  = (const float*)d_in[7];
    const int*   idx_p = (const int*)d_in[8];

    const int N = in_sizes[0] / AH;          // 500000
    float* out      = (float*)d_out;
    float* out_goal = out + (size_t)N * AH;
    float* ws       = (float*)d_ws;          // 128 + 512*4 floats = 8.5 KB

    ig_precompute<<<1, 64, 0, stream>>>(h, ghs, goal, pos, W_emb, b_emb, W_fc, b_fc,
                                        idx_p, out_goal, ws);

    const int n_tiles = N / 16;              // 31250
    const int blocks = 1024;                 // exact 4 blocks/CU fit
    const int total_waves = blocks * 4;
    ig_main<<<blocks, 256, 0, stream>>>(h, goal, pos, ws, idx_p, out,
                                        n_tiles, total_waves);
}

// Round 4
// 260.219 us; speedup vs baseline: 1.3790x; 1.0105x over previous
//
#include <hip/hip_runtime.h>
#include <math.h>

// InteractionGate: N=500000 agents, H=64, D=32.
// Reduction: d1 == 0 always; d2[i] = ||goal[i]-position[i]||;
// new_h[i][j] = sigmoid(C[j] + d2[i]*Wd[j] + dot(h[i], W2[j][:])), W2[j][k]=W_fc[j][64+k].
// h_out[idx] = h[idx]. goal_out (64) computed once.
//
// R8: R5-R7 lesson: widening the read frontier (occupancy OR prefetch depth)
// loses more L3 retention than the concurrency gains. Revert to R4's depth-1
// / 4 blocks/CU structure (best known, 85us, FETCH 71MB) and attack the L3
// equilibrium itself: BOUSTROPHEDON SWEEP. A persistent counter in d_ws
// (incremented by ig_precompute each launch) flips the tile traversal
// direction every launch (t -> n_tiles-1-t). Linear same-direction sweeps
// are cyclic-LRU worst case for cross-dispatch L3 reuse: the head of h is
// always the longest-evicted data. Alternating direction reads the most
// recently resident region first. Direction changes traffic only, never
// results; if the harness zeroes ws, parity sticks and we degrade to R4
// exactly. Tail prefetch uses R7's proven shared row-0 clamp.

#define AH 64
#define AD 32

typedef __attribute__((ext_vector_type(8))) short bf16x8;
typedef __attribute__((ext_vector_type(4))) float f32x4;
typedef __attribute__((ext_vector_type(2))) float f32x2;

__device__ __forceinline__ float sigmoid_fast(float x) {
    return __builtin_amdgcn_rcpf(1.0f + __expf(-x));
}

__device__ __forceinline__ short f2bf(float f) {
    union { float f; unsigned u; } v; v.f = f;
    unsigned r = v.u + 0x7fffu + ((v.u >> 16) & 1u);
    return (short)(r >> 16);
}

// ws layout (floats): [0:64) C, [64:128) Wd, [128:2176) = bf16x8 wfrag[8][64],
// [2176] (as int) = launch counter for sweep direction.
__global__ void ig_precompute(
    const float* __restrict__ h,      // N x 64
    const float* __restrict__ ghs,    // 64
    const float* __restrict__ goal,   // N x 2
    const float* __restrict__ pos,    // N x 2
    const float* __restrict__ W_emb,  // 32 x 2
    const float* __restrict__ b_emb,  // 32
    const float* __restrict__ W_fc,   // 64 x 192
    const float* __restrict__ b_fc,   // 64
    const int*   __restrict__ idx_p,
    float* __restrict__ out_goal,     // 64
    float* __restrict__ ws,
    int*   flip)                      // may be null
{
    const int l = threadIdx.x;        // 0..63
    if (l >= 64) return;
    const int idx = idx_p[0];
    const int m15 = l & 15, q = l >> 4;

    if (l == 0 && flip) flip[0] = flip[0] + 1;   // alternates sweep direction

    // --- C[l], Wd[l], goal_out[l] ---
    const float* wrow = W_fc + l * 192;
    const f32x4* w4  = (const f32x4*)wrow;
    const f32x4* wg4 = (const f32x4*)(wrow + AH);
    const f32x4* h4  = (const f32x4*)(h + (size_t)idx * AH);
    const f32x4* g4  = (const f32x4*)ghs;
    float c = b_fc[l], g = b_fc[l];
    #pragma unroll
    for (int m = 0; m < 16; ++m) {
        const f32x4 hv = h4[m], wv = w4[m];
        const float d = hv[0]*wv[0] + hv[1]*wv[1] + hv[2]*wv[2] + hv[3]*wv[3];
        c += d; g += d;
        const f32x4 gv = g4[m], wv2 = wg4[m];
        g += gv[0]*wv2[0] + gv[1]*wv2[1] + gv[2]*wv2[2] + gv[3]*wv2[3];
    }
    const float px = pos[(size_t)idx*2+0], py = pos[(size_t)idx*2+1];
    const float gx = goal[(size_t)idx*2+0], gy = goal[(size_t)idx*2+1];
    const float dgx = px - gx, dgy = py - gy;
    const float dg = sqrtf(dgx*dgx + dgy*dgy);
    const float* wd1 = wrow + 128;
    const float* wd2 = wrow + 160;
    float wd = 0.f;
    #pragma unroll
    for (int k = 0; k < AD; ++k) {
        const float wsum = W_emb[2*k] + W_emb[2*k+1];
        const float be   = b_emb[k];
        const float w12  = wd1[k] + wd2[k];
        c  += be * w12;
        wd += wsum * wd2[k];
        g  += (dg * wsum + be) * w12;
    }
    ws[l]      = c;
    ws[64 + l] = wd;
    out_goal[l] = sigmoid_fast(g);

    // --- weight A-frags: wfrag[f=mg*2+cc][lane] = W2[mg*16+m15][cc*32+q*8 .. +7] ---
    bf16x8* wf = (bf16x8*)(ws + 128);
    #pragma unroll
    for (int f = 0; f < 8; ++f) {
        const int mg = f >> 1, cc = f & 1;
        const float* src = W_fc + (size_t)(mg*16 + m15) * 192 + AH + cc*32 + q*8;
        const f32x4 s0 = *(const f32x4*)(src);
        const f32x4 s1 = *(const f32x4*)(src + 4);
        bf16x8 b;
        #pragma unroll
        for (int j = 0; j < 4; ++j) { b[j] = f2bf(s0[j]); b[4+j] = f2bf(s1[j]); }
        wf[f * 64 + l] = b;
    }
}

// Load one 16-agent tile's h rows + goal/pos into a register set.
// RB is a ROW-BASE (mapped_tile*16), pre-clamped by the caller.
#define LOAD_TILE(RB, v0, v1, v2, v3, vg, vp) do {                        \
    const int nn_ = (RB) + m15;                                           \
    const float* hp_ = h + (size_t)nn_ * AH;                              \
    v0 = *(const f32x4*)(hp_ + q*8);                                      \
    v1 = *(const f32x4*)(hp_ + q*8 + 4);                                  \
    v2 = *(const f32x4*)(hp_ + 32 + q*8);                                 \
    v3 = *(const f32x4*)(hp_ + 32 + q*8 + 4);                             \
    vg = *(const f32x2*)(goal + 2*(size_t)nn_);                          \
    vp = *(const f32x2*)(pos  + 2*(size_t)nn_);                          \
} while (0)

__global__ __launch_bounds__(256, 4) void ig_main(
    const float* __restrict__ h,      // N x 64
    const float* __restrict__ goal,   // N x 2
    const float* __restrict__ pos,    // N x 2
    const float* __restrict__ ws,     // C, Wd, wfrag
    const int*   __restrict__ idx_p,
    const int*   __restrict__ flip,   // may be null
    float* __restrict__ out,          // N x 64
    int n_tiles, int total_waves)
{
    __shared__ bf16x8 wlds[8][64];              // 8 KB
    __shared__ __align__(16) float cw[128];     // C, Wd

    const int tid  = threadIdx.x;
    const int w    = tid >> 6;
    const int lane = tid & 63;
    const int m15  = lane & 15;
    const int q    = lane >> 4;
    const int idx  = idx_p[0];
    const int dir  = flip ? (flip[0] & 1) : 0;  // wave-uniform
    const int nt1  = n_tiles - 1;

    // Stage ws -> LDS: 128 floats + 512 x 16B chunks.
    if (tid < 128) cw[tid] = ws[tid];
    {
        const f32x4* src = (const f32x4*)(ws + 128);
        f32x4* dst = (f32x4*)wlds;
        dst[tid]       = src[tid];
        dst[tid + 256] = src[tid + 256];
    }
    __syncthreads();

    const int wid = blockIdx.x * 4 + w;
    const int TW  = total_waves;

    // Depth-1 pipeline (R4 structure). Logical tile u sweeps forward;
    // physical tile = dir ? nt1-u : u, so alternate launches sweep h in
    // opposite directions (boustrophedon) for cross-dispatch L3 reuse.
    int t = wid;                                 // wid < 4096 <= n_tiles always
    f32x4 A0, A1, A2, A3; f32x2 Ag, Ap;
    {
        const int mt = dir ? nt1 - t : t;
        LOAD_TILE(mt * 16, A0, A1, A2, A3, Ag, Ap);
    }

    while (t < n_tiles) {
        const int tn = t + TW;
        // Shared hot clamp (rows 0..15) for the tail; R7-proven.
        const int rbn = (tn < n_tiles) ? (dir ? nt1 - tn : tn) * 16 : 0;
        // Prefetch loads issue BEFORE this iteration's stores -> waiting for
        // them next iteration does not drain the stores (in-order vmcnt).
        f32x4 B0, B1, B2, B3; f32x2 Bg, Bp;
        LOAD_TILE(rbn, B0, B1, B2, B3, Bg, Bp);

        const int mt = dir ? nt1 - t : t;
        const int agent = mt * 16 + m15;
        const float dx = Ag[0] - Ap[0], dy = Ag[1] - Ap[1];
        const float d2v = sqrtf(dx*dx + dy*dy);

        bf16x8 bf0, bf1;
        #pragma unroll
        for (int j = 0; j < 4; ++j) {
            bf0[j] = f2bf(A0[j]); bf0[4+j] = f2bf(A1[j]);
            bf1[j] = f2bf(A2[j]); bf1[4+j] = f2bf(A3[j]);
        }

        const size_t rb = (size_t)agent * AH;
        #pragma unroll
        for (int mg = 0; mg < 4; ++mg) {
            const f32x4 c4 = *(const f32x4*)&cw[mg*16 + q*4];
            const f32x4 d4 = *(const f32x4*)&cw[64 + mg*16 + q*4];
            f32x4 acc;
            #pragma unroll
            for (int r = 0; r < 4; ++r) acc[r] = c4[r] + d2v * d4[r];
            acc = __builtin_amdgcn_mfma_f32_16x16x32_bf16(wlds[mg*2+0][lane], bf0, acc, 0, 0, 0);
            acc = __builtin_amdgcn_mfma_f32_16x16x32_bf16(wlds[mg*2+1][lane], bf1, acc, 0, 0, 0);

            f32x4 vv;
            #pragma unroll
            for (int r = 0; r < 4; ++r) vv[r] = sigmoid_fast(acc[r]);
            if (agent == idx) vv = *(const f32x4*)(h + rb + mg*16 + q*4);
            *(f32x4*)(out + rb + mg*16 + q*4) = vv;   // plain cached store
        }

        t = tn;
        A0 = B0; A1 = B1; A2 = B2; A3 = B3; Ag = Bg; Ap = Bp;
    }
}

extern "C" void kernel_launch(void* const* d_in, const int* in_sizes, int n_in,
                              void* d_out, int out_size, void* d_ws, size_t ws_size,
                              hipStream_t stream) {
    const float* h     = (const float*)d_in[0];
    const float* ghs   = (const float*)d_in[1];
    const float* goal  = (const float*)d_in[2];
    const float* pos   = (const float*)d_in[3];
    const float* W_emb = (const float*)d_in[4];
    const float* b_emb = (const float*)d_in[5];
    const float* W_fc  = (const float*)d_in[6];
    const float* b_fc  = (const float*)d_in[7];
    const int*   idx_p = (const int*)d_in[8];

    const int N = in_sizes[0] / AH;          // 500000
    float* out      = (float*)d_out;
    float* out_goal = out + (size_t)N * AH;
    float* ws       = (float*)d_ws;          // 128 + 2048 floats + counter
    int*   flip     = (ws_size >= 2177u * 4u) ? ((int*)d_ws) + 2176 : (int*)0;

    ig_precompute<<<1, 64, 0, stream>>>(h, ghs, goal, pos, W_emb, b_emb, W_fc, b_fc,
                                        idx_p, out_goal, ws, flip);

    const int n_tiles = N / 16;              // 31250
    const int blocks = 1024;                 // exact 4 blocks/CU fit
    const int total_waves = blocks * 4;
    ig_main<<<blocks, 256, 0, stream>>>(h, goal, pos, ws, idx_p, flip, out,
                                        n_tiles, total_waves);
}

// Round 5
// 258.533 us; speedup vs baseline: 1.3880x; 1.0065x over previous
//
#include <hip/hip_runtime.h>
#include <math.h>

// InteractionGate: N=500000 agents, H=64, D=32.
// Reduction: d1 == 0 always; d2[i] = ||goal[i]-position[i]||;
// new_h[i][j] = sigmoid(C[j] + d2[i]*Wd[j] + dot(h[i], W2[j][:])), W2[j][k]=W_fc[j][64+k].
// h_out[idx] = h[idx]. goal_out (64) computed once.
//
// R9: break the frontier<->concurrency coupling. Ladder so far: delivered
// memory throughput rises with in-flight bytes (R8 depth-1/16w: 2.38 TB/s;
// R6/R7 depth-2/16w: 2.55-2.85; R5 32w: 3.1) but every prior concurrency
// increase also widened the prefetch window (depth x generation-width) and
// the L3-retention loss ate the gain. This round: HALVE generation width
// (512 blocks -> TW=2048, 2 blocks/CU) and TRIPLE pipeline depth (depth-3,
// 4 rotating register sets, hand-unrolled x4 so sets stay statically named
// -> no rotation movs, no dynamic indexing). Window = (1+3)*8MB = 32MB,
// IDENTICAL to R8's; in-flight bytes/CU = 8 waves x 3 x 5.1KB = 1.5x R8.
// launch_bounds(256,2) gives 256-VGPR headroom so the pipeline survives
// codegen (R5 lesson: a tight VGPR cap makes the allocator sink prefetches).
// Boustrophedon + shared row-0 tail clamp kept (free).

#define AH 64
#define AD 32

typedef __attribute__((ext_vector_type(8))) short bf16x8;
typedef __attribute__((ext_vector_type(4))) float f32x4;
typedef __attribute__((ext_vector_type(2))) float f32x2;

__device__ __forceinline__ float sigmoid_fast(float x) {
    return __builtin_amdgcn_rcpf(1.0f + __expf(-x));
}

__device__ __forceinline__ short f2bf(float f) {
    union { float f; unsigned u; } v; v.f = f;
    unsigned r = v.u + 0x7fffu + ((v.u >> 16) & 1u);
    return (short)(r >> 16);
}

// ws layout (floats): [0:64) C, [64:128) Wd, [128:2176) = bf16x8 wfrag[8][64],
// [2176] (as int) = launch counter for sweep direction.
__global__ void ig_precompute(
    const float* __restrict__ h,      // N x 64
    const float* __restrict__ ghs,    // 64
    const float* __restrict__ goal,   // N x 2
    const float* __restrict__ pos,    // N x 2
    const float* __restrict__ W_emb,  // 32 x 2
    const float* __restrict__ b_emb,  // 32
    const float* __restrict__ W_fc,   // 64 x 192
    const float* __restrict__ b_fc,   // 64
    const int*   __restrict__ idx_p,
    float* __restrict__ out_goal,     // 64
    float* __restrict__ ws,
    int*   flip)                      // may be null
{
    const int l = threadIdx.x;        // 0..63
    if (l >= 64) return;
    const int idx = idx_p[0];
    const int m15 = l & 15, q = l >> 4;

    if (l == 0 && flip) flip[0] = flip[0] + 1;   // alternates sweep direction

    // --- C[l], Wd[l], goal_out[l] ---
    const float* wrow = W_fc + l * 192;
    const f32x4* w4  = (const f32x4*)wrow;
    const f32x4* wg4 = (const f32x4*)(wrow + AH);
    const f32x4* h4  = (const f32x4*)(h + (size_t)idx * AH);
    const f32x4* g4  = (const f32x4*)ghs;
    float c = b_fc[l], g = b_fc[l];
    #pragma unroll
    for (int m = 0; m < 16; ++m) {
        const f32x4 hv = h4[m], wv = w4[m];
        const float d = hv[0]*wv[0] + hv[1]*wv[1] + hv[2]*wv[2] + hv[3]*wv[3];
        c += d; g += d;
        const f32x4 gv = g4[m], wv2 = wg4[m];
        g += gv[0]*wv2[0] + gv[1]*wv2[1] + gv[2]*wv2[2] + gv[3]*wv2[3];
    }
    const float px = pos[(size_t)idx*2+0], py = pos[(size_t)idx*2+1];
    const float gx = goal[(size_t)idx*2+0], gy = goal[(size_t)idx*2+1];
    const float dgx = px - gx, dgy = py - gy;
    const float dg = sqrtf(dgx*dgx + dgy*dgy);
    const float* wd1 = wrow + 128;
    const float* wd2 = wrow + 160;
    float wd = 0.f;
    #pragma unroll
    for (int k = 0; k < AD; ++k) {
        const float wsum = W_emb[2*k] + W_emb[2*k+1];
        const float be   = b_emb[k];
        const float w12  = wd1[k] + wd2[k];
        c  += be * w12;
        wd += wsum * wd2[k];
        g  += (dg * wsum + be) * w12;
    }
    ws[l]      = c;
    ws[64 + l] = wd;
    out_goal[l] = sigmoid_fast(g);

    // --- weight A-frags: wfrag[f=mg*2+cc][lane] = W2[mg*16+m15][cc*32+q*8 .. +7] ---
    bf16x8* wf = (bf16x8*)(ws + 128);
    #pragma unroll
    for (int f = 0; f < 8; ++f) {
        const int mg = f >> 1, cc = f & 1;
        const float* src = W_fc + (size_t)(mg*16 + m15) * 192 + AH + cc*32 + q*8;
        const f32x4 s0 = *(const f32x4*)(src);
        const f32x4 s1 = *(const f32x4*)(src + 4);
        bf16x8 b;
        #pragma unroll
        for (int j = 0; j < 4; ++j) { b[j] = f2bf(s0[j]); b[4+j] = f2bf(s1[j]); }
        wf[f * 64 + l] = b;
    }
}

// Load one 16-agent tile's h rows + goal/pos into a register set.
// RB is a ROW-BASE (mapped_tile*16), pre-clamped by the caller.
#define LOAD_TILE(RB, v0, v1, v2, v3, vg, vp) do {                        \
    const int nn_ = (RB) + m15;                                           \
    const float* hp_ = h + (size_t)nn_ * AH;                              \
    v0 = *(const f32x4*)(hp_ + q*8);                                      \
    v1 = *(const f32x4*)(hp_ + q*8 + 4);                                  \
    v2 = *(const f32x4*)(hp_ + 32 + q*8);                                 \
    v3 = *(const f32x4*)(hp_ + 32 + q*8 + 4);                             \
    vg = *(const f32x2*)(goal + 2*(size_t)nn_);                           \
    vp = *(const f32x2*)(pos  + 2*(size_t)nn_);                           \
} while (0)

// Prefetch logical tile TT (boustrophedon-mapped, shared row-0 clamp past end).
#define PREF(v0, v1, v2, v3, vg, vp, TT) do {                             \
    const int tf_ = (TT);                                                 \
    const int rb_ = (tf_ < n_tiles) ? (dir ? nt1 - tf_ : tf_) * 16 : 0;   \
    LOAD_TILE(rb_, v0, v1, v2, v3, vg, vp);                               \
} while (0)

// Consume logical tile TT held in register set (V0..V3, VG, VP).
#define CONSUME(V0, V1, V2, V3, VG, VP, TT) do {                          \
    const int mt_ = dir ? nt1 - (TT) : (TT);                              \
    const int agent_ = mt_ * 16 + m15;                                    \
    const float dx_ = VG[0] - VP[0], dy_ = VG[1] - VP[1];                 \
    const float d2v_ = sqrtf(dx_*dx_ + dy_*dy_);                          \
    bf16x8 bf0_, bf1_;                                                    \
    _Pragma("unroll")                                                     \
    for (int j = 0; j < 4; ++j) {                                         \
        bf0_[j] = f2bf(V0[j]); bf0_[4+j] = f2bf(V1[j]);                   \
        bf1_[j] = f2bf(V2[j]); bf1_[4+j] = f2bf(V3[j]);                   \
    }                                                                     \
    const size_t rb2_ = (size_t)agent_ * AH;                              \
    _Pragma("unroll")                                                     \
    for (int mg = 0; mg < 4; ++mg) {                                      \
        const f32x4 c4_ = *(const f32x4*)&cw[mg*16 + q*4];                \
        const f32x4 d4_ = *(const f32x4*)&cw[64 + mg*16 + q*4];           \
        f32x4 acc_;                                                       \
        _Pragma("unroll")                                                 \
        for (int r = 0; r < 4; ++r) acc_[r] = c4_[r] + d2v_ * d4_[r];     \
        acc_ = __builtin_amdgcn_mfma_f32_16x16x32_bf16(wlds[mg*2+0][lane], bf0_, acc_, 0, 0, 0); \
        acc_ = __builtin_amdgcn_mfma_f32_16x16x32_bf16(wlds[mg*2+1][lane], bf1_, acc_, 0, 0, 0); \
        f32x4 vv_;                                                        \
        _Pragma("unroll")                                                 \
        for (int r = 0; r < 4; ++r) vv_[r] = sigmoid_fast(acc_[r]);       \
        if (agent_ == idx) vv_ = *(const f32x4*)(h + rb2_ + mg*16 + q*4); \
        *(f32x4*)(out + rb2_ + mg*16 + q*4) = vv_;   /* plain cached store */ \
    }                                                                     \
} while (0)

__global__ __launch_bounds__(256, 2) void ig_main(
    const float* __restrict__ h,      // N x 64
    const float* __restrict__ goal,   // N x 2
    const float* __restrict__ pos,    // N x 2
    const float* __restrict__ ws,     // C, Wd, wfrag
    const int*   __restrict__ idx_p,
    const int*   __restrict__ flip,   // may be null
    float* __restrict__ out,          // N x 64
    int n_tiles, int total_waves)
{
    __shared__ bf16x8 wlds[8][64];              // 8 KB
    __shared__ __align__(16) float cw[128];     // C, Wd

    const int tid  = threadIdx.x;
    const int w    = tid >> 6;
    const int lane = tid & 63;
    const int m15  = lane & 15;
    const int q    = lane >> 4;
    const int idx  = idx_p[0];
    const int dir  = flip ? (flip[0] & 1) : 0;  // wave-uniform
    const int nt1  = n_tiles - 1;

    // Stage ws -> LDS: 128 floats + 512 x 16B chunks.
    if (tid < 128) cw[tid] = ws[tid];
    {
        const f32x4* src = (const f32x4*)(ws + 128);
        f32x4* dst = (f32x4*)wlds;
        dst[tid]       = src[tid];
        dst[tid + 256] = src[tid + 256];
    }
    __syncthreads();

    const int wid = blockIdx.x * 4 + w;
    const int TW  = total_waves;                 // 2048

    // Depth-3 pipeline, 4 statically-named register sets A..D rotating via
    // 4x hand-unroll (no movs, no dynamic indexing -> stays in registers).
    // Prologue: A=t, B=t+TW, C=t+2TW all < n_tiles (wid<2048, 3*TW=6144).
    int t = wid;
    f32x4 A0, A1, A2, A3; f32x2 Ag, Ap;
    f32x4 B0, B1, B2, B3; f32x2 Bg, Bp;
    f32x4 C0, C1, C2, C3; f32x2 Cg, Cp;
    f32x4 D0, D1, D2, D3; f32x2 Dg, Dp;
    PREF(A0, A1, A2, A3, Ag, Ap, t);
    PREF(B0, B1, B2, B3, Bg, Bp, t + TW);
    PREF(C0, C1, C2, C3, Cg, Cp, t + 2 * TW);

    while (t < n_tiles) {
        PREF(D0, D1, D2, D3, Dg, Dp, t + 3 * TW);
        CONSUME(A0, A1, A2, A3, Ag, Ap, t);
        t += TW; if (t >= n_tiles) break;

        PREF(A0, A1, A2, A3, Ag, Ap, t + 3 * TW);
        CONSUME(B0, B1, B2, B3, Bg, Bp, t);
        t += TW; if (t >= n_tiles) break;

        PREF(B0, B1, B2, B3, Bg, Bp, t + 3 * TW);
        CONSUME(C0, C1, C2, C3, Cg, Cp, t);
        t += TW; if (t >= n_tiles) break;

        PREF(C0, C1, C2, C3, Cg, Cp, t + 3 * TW);
        CONSUME(D0, D1, D2, D3, Dg, Dp, t);
        t += TW;
    }
}

extern "C" void kernel_launch(void* const* d_in, const int* in_sizes, int n_in,
                              void* d_out, int out_size, void* d_ws, size_t ws_size,
                              hipStream_t stream) {
    const float* h     = (const float*)d_in[0];
    const float* ghs   = (const float*)d_in[1];
    const float* goal  = (const float*)d_in[2];
    const float* pos   = (const float*)d_in[3];
    const float* W_emb = (const float*)d_in[4];
    const float* b_emb = (const float*)d_in[5];
    const float* W_fc  = (const float*)d_in[6];
    const float* b_fc  = (const float*)d_in[7];
    const int*   idx_p = (const int*)d_in[8];

    const int N = in_sizes[0] / AH;          // 500000
    float* out      = (float*)d_out;
    float* out_goal = out + (size_t)N * AH;
    float* ws       = (float*)d_ws;          // 128 + 2048 floats + counter
    int*   flip     = (ws_size >= 2177u * 4u) ? ((int*)d_ws) + 2176 : (int*)0;

    ig_precompute<<<1, 64, 0, stream>>>(h, ghs, goal, pos, W_emb, b_emb, W_fc, b_fc,
                                        idx_p, out_goal, ws, flip);

    const int n_tiles = N / 16;              // 31250
    const int blocks = 512;                  // 2 blocks/CU: half generation width
    const int total_waves = blocks * 4;      // TW = 2048
    ig_main<<<blocks, 256, 0, stream>>>(h, goal, pos, ws, idx_p, flip, out,
                                        n_tiles, total_waves);
}

// Round 6
// 255.494 us; speedup vs baseline: 1.4045x; 1.0119x over previous
//
#include <hip/hip_runtime.h>
#include <math.h>

// InteractionGate: N=500000 agents, H=64, D=32.
// Reduction: d1 == 0 always; d2[i] = ||goal[i]-position[i]||;
// new_h[i][j] = sigmoid(C[j] + d2[i]*Wd[j] + dot(h[i], W2[j][:])), W2[j][k]=W_fc[j][64+k].
// h_out[idx] = h[idx]. goal_out (64) computed once.
//
// R10: dense-transaction restructure. R4-R9 invariant: total fabric
// throughput (incl. L3 hits) = 3.0-3.3 TB/s across 8-32 waves/CU and
// prefetch depth 0-3 == exactly HALF the 6.3 TB/s dense-copy ceiling.
// Cause: every VMEM instruction here is fragment-shaped (16 rows x 64B
// per instr, quarter/half cache-line utilization per request), so
// bytes-per-transaction is half of dense and the request-rate-limited
// fabric delivers half BW. Fix: ALL global instructions dense (lane l <->
// bytes l*16, 1KB contiguous per instr); fragment redistribution moves to
// LDS (per-wave private 4KB buffer, chunk-XOR swizzle c^=(row&7) -> all
// four LDS patterns at the uniform b128 structural minimum, no barriers,
// in-order DS per wave handles hazards). Depth-1 pipeline, 1024 blocks,
// bounds(256,4) (VGPR cap 128; R5 lesson). Boustrophedon + clamp kept.

#define AH 64
#define AD 32

typedef __attribute__((ext_vector_type(8))) short bf16x8;
typedef __attribute__((ext_vector_type(4))) float f32x4;
typedef __attribute__((ext_vector_type(2))) float f32x2;

__device__ __forceinline__ float sigmoid_fast(float x) {
    return __builtin_amdgcn_rcpf(1.0f + __expf(-x));
}

__device__ __forceinline__ short f2bf(float f) {
    union { float f; unsigned u; } v; v.f = f;
    unsigned r = v.u + 0x7fffu + ((v.u >> 16) & 1u);
    return (short)(r >> 16);
}

// ws layout (floats): [0:64) C, [64:128) Wd, [128:2176) = bf16x8 wfrag[8][64],
// [2176] (as int) = launch counter for sweep direction.
__global__ void ig_precompute(
    const float* __restrict__ h,      // N x 64
    const float* __restrict__ ghs,    // 64
    const float* __restrict__ goal,   // N x 2
    const float* __restrict__ pos,    // N x 2
    const float* __restrict__ W_emb,  // 32 x 2
    const float* __restrict__ b_emb,  // 32
    const float* __restrict__ W_fc,   // 64 x 192
    const float* __restrict__ b_fc,   // 64
    const int*   __restrict__ idx_p,
    float* __restrict__ out_goal,     // 64
    float* __restrict__ ws,
    int*   flip)                      // may be null
{
    const int l = threadIdx.x;        // 0..63
    if (l >= 64) return;
    const int idx = idx_p[0];
    const int m15 = l & 15, q = l >> 4;

    if (l == 0 && flip) flip[0] = flip[0] + 1;   // alternates sweep direction

    // --- C[l], Wd[l], goal_out[l] ---
    const float* wrow = W_fc + l * 192;
    const f32x4* w4  = (const f32x4*)wrow;
    const f32x4* wg4 = (const f32x4*)(wrow + AH);
    const f32x4* h4  = (const f32x4*)(h + (size_t)idx * AH);
    const f32x4* g4  = (const f32x4*)ghs;
    float c = b_fc[l], g = b_fc[l];
    #pragma unroll
    for (int m = 0; m < 16; ++m) {
        const f32x4 hv = h4[m], wv = w4[m];
        const float d = hv[0]*wv[0] + hv[1]*wv[1] + hv[2]*wv[2] + hv[3]*wv[3];
        c += d; g += d;
        const f32x4 gv = g4[m], wv2 = wg4[m];
        g += gv[0]*wv2[0] + gv[1]*wv2[1] + gv[2]*wv2[2] + gv[3]*wv2[3];
    }
    const float px = pos[(size_t)idx*2+0], py = pos[(size_t)idx*2+1];
    const float gx = goal[(size_t)idx*2+0], gy = goal[(size_t)idx*2+1];
    const float dgx = px - gx, dgy = py - gy;
    const float dg = sqrtf(dgx*dgx + dgy*dgy);
    const float* wd1 = wrow + 128;
    const float* wd2 = wrow + 160;
    float wd = 0.f;
    #pragma unroll
    for (int k = 0; k < AD; ++k) {
        const float wsum = W_emb[2*k] + W_emb[2*k+1];
        const float be   = b_emb[k];
        const float w12  = wd1[k] + wd2[k];
        c  += be * w12;
        wd += wsum * wd2[k];
        g  += (dg * wsum + be) * w12;
    }
    ws[l]      = c;
    ws[64 + l] = wd;
    out_goal[l] = sigmoid_fast(g);

    // --- weight A-frags: wfrag[f=mg*2+cc][lane] = W2[mg*16+m15][cc*32+q*8 .. +7] ---
    bf16x8* wf = (bf16x8*)(ws + 128);
    #pragma unroll
    for (int f = 0; f < 8; ++f) {
        const int mg = f >> 1, cc = f & 1;
        const float* src = W_fc + (size_t)(mg*16 + m15) * 192 + AH + cc*32 + q*8;
        const f32x4 s0 = *(const f32x4*)(src);
        const f32x4 s1 = *(const f32x4*)(src + 4);
        bf16x8 b;
        #pragma unroll
        for (int j = 0; j < 4; ++j) { b[j] = f2bf(s0[j]); b[4+j] = f2bf(s1[j]); }
        wf[f * 64 + l] = b;
    }
}

__global__ __launch_bounds__(256, 4) void ig_main(
    const float* __restrict__ h,      // N x 64
    const float* __restrict__ goal,   // N x 2
    const float* __restrict__ pos,    // N x 2
    const float* __restrict__ ws,     // C, Wd, wfrag
    const int*   __restrict__ idx_p,
    const int*   __restrict__ flip,   // may be null
    float* __restrict__ out,          // N x 64
    int n_tiles, int total_waves)
{
    __shared__ bf16x8 wlds[8][64];               // 8 KB (weight frags)
    __shared__ __align__(16) float cw[128];      // C, Wd
    __shared__ __align__(16) float tbuf[4][1024];// per-wave 4KB tile buffer

    const int tid  = threadIdx.x;
    const int w    = tid >> 6;
    const int lane = tid & 63;
    const int m15  = lane & 15;
    const int q    = lane >> 4;
    const int idx  = idx_p[0];
    const int dir  = flip ? (flip[0] & 1) : 0;   // wave-uniform
    const int nt1  = n_tiles - 1;

    // Stage ws -> LDS: 128 floats + 512 x 16B chunks.
    if (tid < 128) cw[tid] = ws[tid];
    {
        const f32x4* src = (const f32x4*)(ws + 128);
        f32x4* dst = (f32x4*)wlds;
        dst[tid]       = src[tid];
        dst[tid + 256] = src[tid + 256];
    }
    __syncthreads();

    float* tb = tbuf[w];                         // this wave's private buffer

    // Loop-invariant LDS float-offsets. Tile = 16 rows x 16 chunks (16B each);
    // chunk (r,c) lives at float offset (r*16 + (c ^ (r&7))) * 4.
    // stg[k]: dense chunk g = k*64+lane -> r=g>>4, c=g&15. Used for BOTH the
    // input stage-write and the output dense-read (same addresses).
    int stg0, stg1, stg2, stg3;
    {
        const int r0 = 0*4 + (lane >> 4), c = lane & 15;
        const int r1 = r0 + 4, r2 = r0 + 8, r3 = r0 + 12;
        stg0 = (r0*16 + (c ^ (r0 & 7))) * 4;
        stg1 = (r1*16 + (c ^ (r1 & 7))) * 4;
        stg2 = (r2*16 + (c ^ (r2 & 7))) * 4;
        stg3 = (r3*16 + (c ^ (r3 & 7))) * 4;
    }
    const int e = m15 & 7;
    // MFMA fragment chunks: row m15, chunks {2q,2q+1,8+2q,9+2q}.
    const int fb0 = (m15*16 + ((2*q)     ^ e)) * 4;
    const int fb1 = (m15*16 + ((2*q + 1) ^ e)) * 4;
    const int fb2 = (m15*16 + ((8 + 2*q) ^ e)) * 4;
    const int fb3 = (m15*16 + ((9 + 2*q) ^ e)) * 4;
    // Result chunks: row m15, chunk mg*4+q (floats mg*16+q*4 .. +3).
    const int ow0 = (m15*16 + ((0*4 + q) ^ e)) * 4;
    const int ow1 = (m15*16 + ((1*4 + q) ^ e)) * 4;
    const int ow2 = (m15*16 + ((2*4 + q) ^ e)) * 4;
    const int ow3 = (m15*16 + ((3*4 + q) ^ e)) * 4;

    const int wid = blockIdx.x * 4 + w;
    const int TW  = total_waves;                 // 4096

    // Depth-1 pipeline: tile t's 4KB is in regs G0..G3 (dense layout:
    // Gk = tile bytes [k*1024 + lane*16, +16) ), goal/pos in gv/pv.
    int t = wid;                                 // wid < 4096 <= n_tiles
    f32x4 G0, G1, G2, G3; f32x2 gv, pv;
    {
        const int mt = dir ? nt1 - t : t;
        const float* hb = h + (size_t)mt * 1024;
        G0 = *(const f32x4*)(hb +   0 + lane*4);
        G1 = *(const f32x4*)(hb + 256 + lane*4);
        G2 = *(const f32x4*)(hb + 512 + lane*4);
        G3 = *(const f32x4*)(hb + 768 + lane*4);
        const int nn = mt*16 + m15;
        gv = *(const f32x2*)(goal + 2*(size_t)nn);
        pv = *(const f32x2*)(pos  + 2*(size_t)nn);
    }

    while (t < n_tiles) {
        // Dense prefetch of next tile (shared row-0 clamp past end: one 4KB
        // region for ALL waves -> L2-hot, ~free). Issued before anything
        // else so later vmcnt waits never drain this iteration's stores.
        const int tn  = t + TW;
        const int mtn = (tn < n_tiles) ? (dir ? nt1 - tn : tn) : 0;
        f32x4 N0, N1, N2, N3; f32x2 ngv, npv;
        {
            const float* hb = h + (size_t)mtn * 1024;
            N0 = *(const f32x4*)(hb +   0 + lane*4);
            N1 = *(const f32x4*)(hb + 256 + lane*4);
            N2 = *(const f32x4*)(hb + 512 + lane*4);
            N3 = *(const f32x4*)(hb + 768 + lane*4);
            const int nn = mtn*16 + m15;
            ngv = *(const f32x2*)(goal + 2*(size_t)nn);
            npv = *(const f32x2*)(pos  + 2*(size_t)nn);
        }

        // Stage current tile into LDS (compiler waits vmcnt for G-loads,
        // issued last iteration -- newer ops, incl. stores, stay in flight).
        *(f32x4*)(tb + stg0) = G0;
        *(f32x4*)(tb + stg1) = G1;
        *(f32x4*)(tb + stg2) = G2;
        *(f32x4*)(tb + stg3) = G3;

        // Read MFMA fragments (in-order DS per wave; compiler inserts lgkm).
        const f32x4 b0 = *(const f32x4*)(tb + fb0);
        const f32x4 b1 = *(const f32x4*)(tb + fb1);
        const f32x4 b2 = *(const f32x4*)(tb + fb2);
        const f32x4 b3 = *(const f32x4*)(tb + fb3);

        const int mt = dir ? nt1 - t : t;
        const int agent = mt*16 + m15;
        const float dx = gv[0] - pv[0], dy = gv[1] - pv[1];
        const float d2v = sqrtf(dx*dx + dy*dy);

        bf16x8 bf0, bf1;
        #pragma unroll
        for (int j = 0; j < 4; ++j) {
            bf0[j] = f2bf(b0[j]); bf0[4+j] = f2bf(b1[j]);
            bf1[j] = f2bf(b2[j]); bf1[4+j] = f2bf(b3[j]);
        }

        const size_t rb = (size_t)agent * AH;
        #pragma unroll
        for (int mg = 0; mg < 4; ++mg) {
            const f32x4 c4 = *(const f32x4*)&cw[mg*16 + q*4];
            const f32x4 d4 = *(const f32x4*)&cw[64 + mg*16 + q*4];
            f32x4 acc;
            #pragma unroll
            for (int r = 0; r < 4; ++r) acc[r] = c4[r] + d2v * d4[r];
            acc = __builtin_amdgcn_mfma_f32_16x16x32_bf16(wlds[mg*2+0][lane], bf0, acc, 0, 0, 0);
            acc = __builtin_amdgcn_mfma_f32_16x16x32_bf16(wlds[mg*2+1][lane], bf1, acc, 0, 0, 0);

            f32x4 vv;
            #pragma unroll
            for (int r = 0; r < 4; ++r) vv[r] = sigmoid_fast(acc[r]);
            if (agent == idx) vv = *(const f32x4*)(h + rb + mg*16 + q*4);
            const int owx = (mg == 0) ? ow0 : (mg == 1) ? ow1 : (mg == 2) ? ow2 : ow3;
            *(f32x4*)(tb + owx) = vv;            // LDS result write (swizzled)
        }

        // Dense read-back + dense global store (full 128B lines/instr).
        const f32x4 S0 = *(const f32x4*)(tb + stg0);
        const f32x4 S1 = *(const f32x4*)(tb + stg1);
        const f32x4 S2 = *(const f32x4*)(tb + stg2);
        const f32x4 S3 = *(const f32x4*)(tb + stg3);
        float* ob = out + (size_t)mt * 1024;
        *(f32x4*)(ob +   0 + lane*4) = S0;
        *(f32x4*)(ob + 256 + lane*4) = S1;
        *(f32x4*)(ob + 512 + lane*4) = S2;
        *(f32x4*)(ob + 768 + lane*4) = S3;

        t = tn;
        G0 = N0; G1 = N1; G2 = N2; G3 = N3; gv = ngv; pv = npv;
    }
}

extern "C" void kernel_launch(void* const* d_in, const int* in_sizes, int n_in,
                              void* d_out, int out_size, void* d_ws, size_t ws_size,
                              hipStream_t stream) {
    const float* h     = (const float*)d_in[0];
    const float* ghs   = (const float*)d_in[1];
    const float* goal  = (const float*)d_in[2];
    const float* pos   = (const float*)d_in[3];
    const float* W_emb = (const float*)d_in[4];
    const float* b_emb = (const float*)d_in[5];
    const float* W_fc  = (const float*)d_in[6];
    const float* b_fc  = (const float*)d_in[7];
    const int*   idx_p = (const int*)d_in[8];

    const int N = in_sizes[0] / AH;          // 500000
    float* out      = (float*)d_out;
    float* out_goal = out + (size_t)N * AH;
    float* ws       = (float*)d_ws;          // 128 + 2048 floats + counter
    int*   flip     = (ws_size >= 2177u * 4u) ? ((int*)d_ws) + 2176 : (int*)0;

    ig_precompute<<<1, 64, 0, stream>>>(h, ghs, goal, pos, W_emb, b_emb, W_fc, b_fc,
                                        idx_p, out_goal, ws, flip);

    const int n_tiles = N / 16;              // 31250
    const int blocks = 1024;                 // 4 blocks/CU (LDS 24.5KB/block)
    const int total_waves = blocks * 4;      // TW = 4096
    ig_main<<<blocks, 256, 0, stream>>>(h, goal, pos, ws, idx_p, flip, out,
                                        n_tiles, total_waves);
}